// Round 13
// baseline (68.618 us; speedup 1.0000x reference)
//
#include <hip/hip_runtime.h>

#define T 16
#define E 30
#define H 50
#define VOCAB 100
#define ROWS 208        // 13 tiles of 16 rows
#define K1 1.44269504089f   // log2(e)
#define K2 2.88539008178f   // 2*log2(e)
#define NTILE 13

typedef _Float16 v8hf __attribute__((ext_vector_type(8)));
typedef float v4f __attribute__((ext_vector_type(4)));

extern "C" __device__ float __ocml_native_exp2_f32(float);
__device__ __forceinline__ float e2(float x)   { return __ocml_native_exp2_f32(x); }
__device__ __forceinline__ float rcpf(float x) { return __builtin_amdgcn_rcpf(x); }

// Lane-local unit assignment: tile i, row-group lgc, gate g  <->  unit u = lgc*13 + i.
// tbl row r = 16*tile + rho, rho = lgc*4 + gate. Pre-scaled by -log2e (i,f,o) / 2log2e (g).
__global__ void build_tbl(const float* __restrict__ emb,
                          const float* __restrict__ w_ih,
                          const float* __restrict__ b_ih,
                          const float* __restrict__ b_hh,
                          float* __restrict__ tbl) {
    int idx = blockIdx.x * blockDim.x + threadIdx.x;
    if (idx >= VOCAB * ROWS) return;
    int v = idx / ROWS, r = idx % ROWS;
    int tile = r >> 4, rho = r & 15;
    int lgc = rho >> 2, gate = rho & 3;
    int u = lgc * 13 + tile;
    float s = 0.f;
    if (u < H) {
        int orig = gate * H + u;
        s = b_ih[orig] + b_hh[orig];
        const float* er = emb + v * E;
        const float* wr = w_ih + orig * E;
#pragma unroll
        for (int e = 0; e < E; ++e) s += er[e] * wr[e];
        s *= (gate == 2) ? K2 : -K1;
    }
    tbl[idx] = s;
}

// Zero-LDS LSTM, phase-structured: all MFMAs -> all loads -> all exp2 ->
// all cell-updates -> all h — so the 13 per-tile trans chains interleave
// instead of serializing under register pressure. VGPR budget deliberately
// high (grid caps occupancy at 2 waves/SIMD regardless).
__global__ __launch_bounds__(256, 1) void lstm_mfma(
    const int* __restrict__ ids,     // [NSEQ, T]
    const float* __restrict__ tbl,   // [2][VOCAB][ROWS]
    const float* __restrict__ whh_f, // [200][50]
    const float* __restrict__ whh_r, // [200][50]
    float* __restrict__ out)         // [NSEQ, 100]
{
    const int tid = threadIdx.x;
    const int lane = tid & 63;
    const int wave = tid >> 6;
    const int l15 = lane & 15;       // seq within wave / C col
    const int lg = lane >> 4;        // k-/B-slot group
    const int b = blockIdx.x;
    const int dir = b >> 8;          // 512 blocks: 0..255 fwd, 256..511 rev
    const int seq = (b & 255) * 64 + wave * 16 + l15;

    const float* __restrict__ whh = dir ? whh_r : whh_f;
    const float* __restrict__ tb  = tbl + dir * (VOCAB * ROWS);
    const int* __restrict__ myids = ids + seq * T;

    // ragged length -> capture step (per lane's own sequence)
    int capt;
    {
        const int4* q = (const int4*)myids;
        int4 a0 = q[0], a1 = q[1], a2 = q[2], a3 = q[3];
        int len = (a0.x != 0) + (a0.y != 0) + (a0.z != 0) + (a0.w != 0)
                + (a1.x != 0) + (a1.y != 0) + (a1.z != 0) + (a1.w != 0)
                + (a2.x != 0) + (a2.y != 0) + (a2.z != 0) + (a2.w != 0)
                + (a3.x != 0) + (a3.y != 0) + (a3.z != 0) + (a3.w != 0);
        capt = dir ? (T - 1) : ((len > 1) ? (len - 1) : 0);
    }

    // A-fragments: lane(lg,l15) tile i kh: af[j] = A[16i + l15][kh*32 + lg*8 + j]
    //   row 16i+l15: gate = l15&3 of unit urow = (l15>>2)*13 + i
    //   col k-slot (kh,lg,j): unit ucol = lg*13 + kh*8 + j  (zeroed if pad)
    const int gate = l15 & 3;
    const int rbase = (l15 >> 2) * 13;
    const float sc = (gate == 2) ? K2 : -K1;
    v8hf afrag[NTILE][2];
#pragma unroll
    for (int i = 0; i < NTILE; ++i) {
        const int urow = rbase + i;
        const bool vrow = (urow < H);
        const int worow = (gate * H + (vrow ? urow : 0)) * H;
#pragma unroll
        for (int kh = 0; kh < 2; ++kh) {
            v8hf af;
#pragma unroll
            for (int j = 0; j < 8; ++j) {
                const int m = kh * 8 + j;
                const int ucol = lg * 13 + m;
                const bool vcol = (m < NTILE) && (ucol < H);
                af[j] = (_Float16)((vrow && vcol) ? sc * whh[worow + ucol] : 0.f);
            }
            afrag[i][kh] = af;
        }
    }

    float cs[NTILE];
#pragma unroll
    for (int i = 0; i < NTILE; ++i) cs[i] = 0.f;

    v8hf b0 = (v8hf)(_Float16)0.f;   // h(t-1) units lg*13+0..7   (t=0: zeros)
    v8hf b1 = (v8hf)(_Float16)0.f;   // h(t-1) units lg*13+8..12 + pads

    // prefetch tv for t=0
    v4f tv[NTILE];
    {
        const int id0 = myids[dir ? (T - 1) : 0];
        const float* __restrict__ trow = tb + id0 * ROWS;
#pragma unroll
        for (int i = 0; i < NTILE; ++i)
            tv[i] = *(const v4f*)(trow + i * 16 + lg * 4);
    }

#pragma unroll 1   // rolled t-loop
    for (int t = 0; t < T; ++t) {
        int tn = dir ? (T - 2 - t) : (t + 1);
        if (t == T - 1) tn = dir ? 0 : (T - 1);    // dummy valid index
        const int id_next = myids[tn];
        const float* __restrict__ trow_n = tb + id_next * ROWS;
        const bool cap = (t == capt);

        // ---- phase 1: all 26 MFMAs (c[13] live together) ----
        v4f c[NTILE];
#pragma unroll
        for (int i = 0; i < NTILE; ++i) {
            c[i] = __builtin_amdgcn_mfma_f32_16x16x32_f16(afrag[i][0], b0, tv[i], 0, 0, 0);
            c[i] = __builtin_amdgcn_mfma_f32_16x16x32_f16(afrag[i][1], b1, c[i], 0, 0, 0);
        }

        // ---- phase 2: prefetch next step's table rows ----
#pragma unroll
        for (int i = 0; i < NTILE; ++i)
            tv[i] = *(const v4f*)(trow_n + i * 16 + lg * 4);

        // ---- phase 3: all gate exponentials (52 exp2, fully parallel) ----
        float ei[NTILE], ef[NTILE], eg[NTILE], eo[NTILE];
#pragma unroll
        for (int i = 0; i < NTILE; ++i) {
            ei[i] = e2(c[i][0]);
            ef[i] = e2(c[i][1]);
            eg[i] = e2(c[i][2]);
            eo[i] = e2(c[i][3]);
        }

        // ---- phase 4: all cell updates (13 rcp chains interleave) ----
        float cn_[NTILE];
#pragma unroll
        for (int i = 0; i < NTILE; ++i) {
            float ai  = 1.f + ei[i];
            float bf  = 1.f + ef[i];
            float gp  = eg[i] + 1.f;
            float gm2 = fmaf(K2, eg[i], -K2);            // K2*(eg-1)
            float num = fmaf(cs[i] * ai, gp, gm2 * bf);
            float rD  = rcpf(ai * bf * gp);
            cn_[i] = num * rD;                            // cs' = K2 * c_new
            cs[i] = cn_[i];
        }

        // ---- phase 5: all h (13 exp2 + 13 rcp, parallel) ----
        float hn[NTILE];
#pragma unroll
        for (int i = 0; i < NTILE; ++i) {
            float ec = e2(cn_[i]);                        // e^(2 c_new)
            hn[i] = (ec - 1.f) * rcpf((1.f + eo[i]) * (ec + 1.f));
        }

        // ---- phase 6: capture store + pack into next-step B fragments ----
        if (cap) {
#pragma unroll
            for (int i = 0; i < NTILE; ++i)
                if (i < 11 || lg < 3)
                    out[seq * 100 + dir * H + lg * NTILE + i] = hn[i];
        }
        // pad B-slots need no zeroing: their A columns are zero.
        v8hf nb0, nb1;
#pragma unroll
        for (int j = 0; j < 8; ++j) nb0[j] = (_Float16)hn[j];
#pragma unroll
        for (int j = 0; j < 5; ++j) nb1[j] = (_Float16)hn[8 + j];
        nb1[5] = (_Float16)0.f; nb1[6] = (_Float16)0.f; nb1[7] = (_Float16)0.f;
        b0 = nb0; b1 = nb1;
    }
}

extern "C" void kernel_launch(void* const* d_in, const int* in_sizes, int n_in,
                              void* d_out, int out_size, void* d_ws, size_t ws_size,
                              hipStream_t stream) {
    const int*   char_ids = (const int*)d_in[0];
    const float* emb      = (const float*)d_in[1];
    const float* w_ih_f   = (const float*)d_in[2];
    const float* w_hh_f   = (const float*)d_in[3];
    const float* b_ih_f   = (const float*)d_in[4];
    const float* b_hh_f   = (const float*)d_in[5];
    const float* w_ih_r   = (const float*)d_in[6];
    const float* w_hh_r   = (const float*)d_in[7];
    const float* b_ih_r   = (const float*)d_in[8];
    const float* b_hh_r   = (const float*)d_in[9];
    float* out = (float*)d_out;
    float* tbl = (float*)d_ws; // [2][VOCAB][ROWS] f32 = 166.4 KB

    const int nt = VOCAB * ROWS; // 20800
    build_tbl<<<(nt + 255) / 256, 256, 0, stream>>>(emb, w_ih_f, b_ih_f, b_hh_f, tbl);
    build_tbl<<<(nt + 255) / 256, 256, 0, stream>>>(emb, w_ih_r, b_ih_r, b_hh_r, tbl + nt);
    // 512 blocks x 256: 4 fully independent 16-seq waves per block, zero LDS
    lstm_mfma<<<512, 256, 0, stream>>>(char_ids, tbl, w_hh_f, w_hh_r, out);
}